// Round 4
// baseline (371.440 us; speedup 1.0000x reference)
//
#include <hip/hip_runtime.h>

// EEGGraphClf graph-loss, fused single pass over A. B=64, N=1024, D=16.
//
// loss[b] = 0.2 * [ sum_n deg_n*||f_n||^2 - sum_j f_j . w_j ] / N^2
//         - 0.1 * sum_n log(deg_n + 1e-12) / N
//         + 0.1 * sum_{n,j} A[n,j]^2 / N^2
//   with w_j = sum_n A[n,j] * f_n   (register accumulators, dotted once at end)
//
// 16 blocks/batch, block = 64 rows x 1024 cols, 512 threads, 2 cols/thread.
//
// R3 post-mortem: kernel ~86us (= R0's kernel exactly) at ~3.1 TB/s, 2x the
// 43us A-stream roofline. Both structures shared: (a) nontemporal A loads
// (possible L2-bypass -> read-BW penalty, never A/B'd), (b) f via s_load:
// SMEM returns out-of-order so every f-consume is lgkmcnt(0), draining the
// next-row f-prefetch -> ~250cy exposed per row per wave.
// R4: (1) plain (allocating) A loads; (2) f via v_readlane from a per-lane
// F-row register cache (lane l holds F[n0+l][0..15], 16 VGPR; 16 readlanes
// per row -> SGPRs; zero latency, zero lgkm); (3) A-prefetch depth 8 with
// counted vmcnt (only vmem in the loop). Loop lgkm = 2 deg swizzles + 1
// conditional ds_write only (in-order DS).

#define NN      1024
#define DD      16
#define ROWS    64
#define TPB     512
#define GRPS    128        // 512 threads / 4 = 128 deg groups per row
#define SMOOTHR 0.2f
#define DEGRR   0.1f
#define SPARSR  0.1f
#define EPSV    1e-12f

typedef float vf4 __attribute__((ext_vector_type(4)));
typedef float vf2 __attribute__((ext_vector_type(2)));

__global__ __launch_bounds__(TPB, 4)
void graph_loss_kernel(const float* __restrict__ A,
                       const float* __restrict__ F,
                       float* __restrict__ out) {
    __shared__ float degq[ROWS][GRPS + 1];   // 33 KB, stride 129
    __shared__ float wred[8][2];

    const int tid = threadIdx.x;
    const int bid = blockIdx.x;
    const int b   = bid >> 4;
    const int n0  = (bid & 15) * ROWS;

    const float* __restrict__ Fb = F + (size_t)b * NN * DD;
    const float* __restrict__ Ab = A + ((size_t)b * NN + n0) * NN;

    // ---- per-lane F-row cache: lane l holds F[n0+l][0..15] (16 VGPR) ----
    float fr[16];
    {
        const int lane = tid & 63;
        const vf4* p = (const vf4*)(Fb + (size_t)(n0 + lane) * DD);
        const vf4 t0 = p[0], t1 = p[1], t2 = p[2], t3 = p[3];
        fr[0]=t0.x;  fr[1]=t0.y;  fr[2]=t0.z;  fr[3]=t0.w;
        fr[4]=t1.x;  fr[5]=t1.y;  fr[6]=t1.z;  fr[7]=t1.w;
        fr[8]=t2.x;  fr[9]=t2.y;  fr[10]=t2.z; fr[11]=t2.w;
        fr[12]=t3.x; fr[13]=t3.y; fr[14]=t3.z; fr[15]=t3.w;
    }

    // ---- per-thread state: w0/w1 = 32 VGPR accumulators ----
    float w0[16], w1[16];
    #pragma unroll
    for (int k = 0; k < 16; ++k) { w0[k] = 0.f; w1[k] = 0.f; }

    float sq = 0.f;
    const float* __restrict__ arow = Ab + 2 * tid;
    const int  g       = tid >> 2;           // 4 threads = 8 cols per group
    const bool deglane = (tid & 3) == 0;

    #define LOADR(r) (*(const vf2*)(arow + (size_t)(r) * NN))
    // broadcast F[n0+rr][k] from lane rr of the F-row cache (uniform -> SGPR)
    #define RL(v, l) __builtin_bit_cast(float, \
        __builtin_amdgcn_readlane(__builtin_bit_cast(int, (v)), (l)))
    #define COMPUTE(av, rr)                                                  \
        do {                                                                 \
            float s_ = av.x + av.y;                                          \
            s_ += __shfl_xor(s_, 1);                                         \
            s_ += __shfl_xor(s_, 2);                                         \
            if (deglane) degq[(rr)][g] = s_;                                 \
            sq += av.x * av.x + av.y * av.y;                                 \
            _Pragma("unroll")                                                \
            for (int k = 0; k < 16; ++k) {                                   \
                const float fk = RL(fr[k], (rr));                            \
                w0[k] += av.x * fk;                                          \
                w1[k] += av.y * fk;                                          \
            }                                                                \
        } while (0)

    // ---- prologue: 8-row A prefetch (counted vmcnt, only vmem in loop) ----
    vf2 a[8];
    #pragma unroll
    for (int i = 0; i < 8; ++i) a[i] = LOADR(i);

    // ---- main loop: 8 rows/iter, zero barriers ----
    #pragma unroll 1
    for (int r = 0; r < ROWS - 8; r += 8) {
        #pragma unroll
        for (int i = 0; i < 8; ++i) {
            COMPUTE(a[i], r + i);
            a[i] = LOADR(r + 8 + i);
        }
    }
    // epilogue: rows ROWS-8..ROWS-1
    #pragma unroll
    for (int i = 0; i < 8; ++i) COMPUTE(a[i], ROWS - 8 + i);

    #undef LOADR
    #undef RL
    #undef COMPUTE

    // ---- finalize degrees: deg_n, log(deg_n), deg_n*||f_n||^2 (wave 0) ----
    __syncthreads();
    float lg = 0.f, dfn = 0.f;
    if (tid < ROWS) {
        float s = 0.f;
        #pragma unroll 1
        for (int i = 0; i < GRPS; ++i) s += degq[tid][i];  // stride 129
        lg = logf(s + EPSV);
        float t = 0.f;
        #pragma unroll
        for (int k = 0; k < 16; ++k) t += fr[k] * fr[k];   // lane tid holds row n0+tid
        dfn = s * t;
    }

    // ---- dot own columns' features against w (8 vf4 global loads, once) ----
    float dot = 0.f;
    {
        const vf4* __restrict__ P = (const vf4*)(Fb + (size_t)(2 * tid) * DD);
        #pragma unroll
        for (int q = 0; q < 4; ++q) {
            const vf4 f = P[q];
            dot += f.x * w0[4*q] + f.y * w0[4*q+1] + f.z * w0[4*q+2] + f.w * w0[4*q+3];
        }
        #pragma unroll
        for (int q = 0; q < 4; ++q) {
            const vf4 f = P[4 + q];
            dot += f.x * w1[4*q] + f.y * w1[4*q+1] + f.z * w1[4*q+2] + f.w * w1[4*q+3];
        }
    }

    // ---- block reduction: dot/sq across 8 waves; lg/dfn live in wave 0 ----
    #pragma unroll
    for (int m = 1; m < 64; m <<= 1) {
        dot += __shfl_xor(dot, m);
        sq  += __shfl_xor(sq, m);
        lg  += __shfl_xor(lg, m);
        dfn += __shfl_xor(dfn, m);
    }
    const int wv = tid >> 6;
    if ((tid & 63) == 0) { wred[wv][0] = dot; wred[wv][1] = sq; }
    __syncthreads();
    if (tid == 0) {
        float Dt = 0.f, Q = 0.f;
        #pragma unroll
        for (int i = 0; i < 8; ++i) { Dt += wred[i][0]; Q += wred[i][1]; }
        const float denom = (float)NN * (float)NN;
        const float contrib = SMOOTHR * (dfn - Dt) / denom
                            - DEGRR * lg / (float)NN
                            + SPARSR * Q / denom;
        atomicAdd(out + b, contrib);
    }
}

extern "C" void kernel_launch(void* const* d_in, const int* in_sizes, int n_in,
                              void* d_out, int out_size, void* d_ws, size_t ws_size,
                              hipStream_t stream) {
    const float* A = (const float*)d_in[0];   // out_adj [B,N,N]
    const float* F = (const float*)d_in[1];   // features [B,N,D]
    float* out = (float*)d_out;               // [B]

    const int B = out_size;                   // 64
    (void)hipMemsetAsync(d_out, 0, (size_t)B * sizeof(float), stream);
    graph_loss_kernel<<<dim3(B * (NN / ROWS)), dim3(TPB), 0, stream>>>(A, F, out);
}